// Round 14
// baseline (19078.229 us; speedup 1.0000x reference)
//
#include <hip/hip_runtime.h>
#include <stdint.h>

#pragma clang fp contract(off)

#define B_ 8192
#define V_ 1024
#define H_ 128
#define CD_ 16
#define WID_ 64
#define NOUT_ 2304
#define STEPS_ 16

typedef float f32x2 __attribute__((ext_vector_type(2)));

// packed f32 fma: per-half IEEE rn fma — bit-identical to the certified
// scalar __fmaf_rn(wv, bit, acc) applied to each half independently.
__device__ __forceinline__ void pkfma(f32x2& acc, f32x2 wv, f32x2 bf2) {
  asm("v_pk_fma_f32 %0, %1, %2, %0" : "+v"(acc) : "v"(wv), "v"(bf2));
}

// ---------------- threefry2x32 (JAX-compatible, 20 rounds) ----------------
__host__ __device__ __forceinline__ void tf2x32(uint32_t k0, uint32_t k1,
                                                uint32_t x0, uint32_t x1,
                                                uint32_t* o0, uint32_t* o1) {
  uint32_t ks2 = k0 ^ k1 ^ 0x1BD11BDAu;
#define RL_(v, d) (((v) << (d)) | ((v) >> (32 - (d))))
#define RND_(a) { x0 += x1; x1 = RL_(x1, a); x1 ^= x0; }
  x0 += k0; x1 += k1;
  RND_(13) RND_(15) RND_(26) RND_(6)
  x0 += k1; x1 += ks2 + 1u;
  RND_(17) RND_(29) RND_(16) RND_(24)
  x0 += ks2; x1 += k0 + 2u;
  RND_(13) RND_(15) RND_(26) RND_(6)
  x0 += k0; x1 += k1 + 3u;
  RND_(17) RND_(29) RND_(16) RND_(24)
  x0 += k1; x1 += ks2 + 4u;
  RND_(13) RND_(15) RND_(26) RND_(6)
  x0 += ks2; x1 += k0 + 5u;
#undef RND_
#undef RL_
  *o0 = x0; *o1 = x1;
}

struct Keys { uint32_t a[6]; }; // (k1a,k1b,k2a,k2b,k3a,k3b)

// certified: partitionable threefry, bits = x0 ^ x1
__device__ __forceinline__ uint32_t draw_bits(uint32_t ka, uint32_t kb, uint32_t j) {
  uint32_t x0, x1;
  tf2x32(ka, kb, 0u, j, &x0, &x1);
  return x0 ^ x1;
}

__device__ __forceinline__ float bits_to_u(uint32_t bits) {
  return __fsub_rn(__uint_as_float((bits >> 9) | 0x3f800000u), 1.0f); // exact
}

// certified config A: XLA Cephes exp, plain mul/add
__device__ __forceinline__ float exp_a(float x) {
  float xc = fminf(fmaxf(x, -88.3762626647949f), 88.3762626647950f);
  float fx = floorf(__fadd_rn(__fmul_rn(xc, 1.44269504088896341f), 0.5f));
  float xr = __fsub_rn(xc, __fmul_rn(0.693359375f, fx));
  xr = __fsub_rn(xr, __fmul_rn(-2.12194440e-4f, fx));
  float zz = __fmul_rn(xr, xr);
  float y = 1.9875691500E-4f;
  y = __fadd_rn(__fmul_rn(y, xr), 1.3981999507E-3f);
  y = __fadd_rn(__fmul_rn(y, xr), 8.3334519073E-3f);
  y = __fadd_rn(__fmul_rn(y, xr), 4.1665795894E-2f);
  y = __fadd_rn(__fmul_rn(y, xr), 1.6666665459E-1f);
  y = __fadd_rn(__fmul_rn(y, xr), 5.0000001201E-1f);
  y = __fadd_rn(__fmul_rn(y, zz), xr);
  y = __fadd_rn(y, 1.0f);
  int n = (int)fx;
  float sc = __int_as_float((n + 127) << 23);
  return __fmul_rn(y, sc);
}

// certified config A: XLA EmitFastTanh, plain path (for the MLP tanh)
__device__ __forceinline__ float tanh_a(float xin) {
  float x = fmaxf(fminf(xin, 7.90531110763549805f), -7.90531110763549805f);
  float x2 = __fmul_rn(x, x);
  float p = __fadd_rn(__fmul_rn(x2, -2.76076847742355e-16f), 2.00018790482477e-13f);
  p = __fadd_rn(__fmul_rn(x2, p), -8.60467152213735e-11f);
  p = __fadd_rn(__fmul_rn(x2, p), 5.12229709037114e-08f);
  p = __fadd_rn(__fmul_rn(x2, p), 1.48572235717979e-05f);
  p = __fadd_rn(__fmul_rn(x2, p), 6.37261928875436e-04f);
  p = __fadd_rn(__fmul_rn(x2, p), 4.89352455891786e-03f);
  p = __fmul_rn(x, p);
  float q = __fadd_rn(__fmul_rn(x2, 1.19825839466702e-06f), 1.18534705686654e-04f);
  q = __fadd_rn(__fmul_rn(x2, q), 2.26843463243900e-03f);
  q = __fadd_rn(__fmul_rn(x2, q), 4.89352518554385e-03f);
  float r = p / q;
  if (fabsf(xin) < 0.0004f) r = xin;
  return r;
}

// certified: exp-form logistic
__device__ __forceinline__ float sigmoid_a(float z) {
  float e = exp_a(-z);
  return 1.0f / __fadd_rn(1.0f, e);
}

// ---------------- setup kernels ----------------
__global__ void k_transpose(const float* __restrict__ W, float* __restrict__ WT,
                            const float* __restrict__ fc2w, float* __restrict__ fc2T) {
  int i = blockIdx.x * blockDim.x + threadIdx.x;
  if (i < V_ * H_) { int v = i / H_, h = i % H_; WT[h * V_ + v] = W[i]; }
  if (i < NOUT_ * WID_) { int j = i / WID_, w = i % WID_; fc2T[w * NOUT_ + j] = fc2w[i]; }
}

__global__ void k_temps(const float* __restrict__ falloff, float* __restrict__ temps) {
  int t = threadIdx.x;
  if (t < 16) {
    float arg = __fmul_rn(*falloff, __fsub_rn((float)t, 8.0f));
    float e = exp_a(arg);
    float s = 1.0f / __fadd_rn(1.0f, e);
    temps[t] = __fadd_rn(1.0f, __fmul_rn(4.0f, s));
  }
}

__global__ void k_mlp1(const float* __restrict__ cond, const float* __restrict__ fc1w,
                       const float* __restrict__ fc1b, float* __restrict__ xout) {
  int idx = blockIdx.x * blockDim.x + threadIdx.x;
  if (idx >= B_ * WID_) return;
  int row = idx >> 6, w = idx & 63;
  float acc = 0.0f;
  for (int k = 0; k < CD_; k++) acc = __fmaf_rn(cond[row * CD_ + k], fc1w[w * CD_ + k], acc);
  float z = __fadd_rn(acc, fc1b[w]);
  xout[idx] = tanh_a(z);
}

__global__ __launch_bounds__(128) void k_mlp2b(const float* __restrict__ xmlp,
                       const float* __restrict__ fc2T, const float* __restrict__ fc2b,
                       const float* __restrict__ bvec, float* __restrict__ b_mod) {
  __shared__ float xs[32][WID_];
  int jbase = blockIdx.x * 128;
  int r0 = blockIdx.y * 32;
  int tid = threadIdx.x;
  for (int t = tid; t < 32 * WID_; t += 128)
    xs[t >> 6][t & 63] = xmlp[(r0 + (t >> 6)) * WID_ + (t & 63)];
  __syncthreads();
  int j = jbase + tid;
  float accg[32], accb[32];
#pragma unroll
  for (int r = 0; r < 32; r++) { accg[r] = 0.0f; accb[r] = 0.0f; }
  for (int w = 0; w < WID_; w++) {
    float fg = fc2T[w * NOUT_ + j];
    float fb = fc2T[w * NOUT_ + 1024 + j];
#pragma unroll
    for (int r = 0; r < 32; r++) {
      float xv = xs[r][w];
      accg[r] = __fmaf_rn(xv, fg, accg[r]);
      accb[r] = __fmaf_rn(xv, fb, accb[r]);
    }
  }
  float bj = bvec[j];
  float biasg = fc2b[j], biasb = fc2b[1024 + j];
#pragma unroll
  for (int r = 0; r < 32; r++) {
    float g = __fadd_rn(accg[r], biasg);
    float bb = __fadd_rn(accb[r], biasb);
    float t1 = __fadd_rn(1.0f, g);
    b_mod[(r0 + r) * V_ + j] = __fadd_rn(__fmul_rn(t1, bj), bb);
  }
}

__global__ __launch_bounds__(128) void k_mlp2c(const float* __restrict__ xmlp,
                       const float* __restrict__ fc2T, const float* __restrict__ fc2b,
                       const float* __restrict__ cvec, float* __restrict__ c_mod) {
  __shared__ float xs[32][WID_];
  int r0 = blockIdx.y * 32;
  int tid = threadIdx.x; // 0..127
  for (int t = tid; t < 32 * WID_; t += 128)
    xs[t >> 6][t & 63] = xmlp[(r0 + (t >> 6)) * WID_ + (t & 63)];
  __syncthreads();
  float accg[32], accb[32];
#pragma unroll
  for (int r = 0; r < 32; r++) { accg[r] = 0.0f; accb[r] = 0.0f; }
  for (int w = 0; w < WID_; w++) {
    float fg = fc2T[w * NOUT_ + 2048 + tid];
    float fb = fc2T[w * NOUT_ + 2176 + tid];
#pragma unroll
    for (int r = 0; r < 32; r++) {
      float xv = xs[r][w];
      accg[r] = __fmaf_rn(xv, fg, accg[r]);
      accb[r] = __fmaf_rn(xv, fb, accb[r]);
    }
  }
  float cj = cvec[tid];
  float biasg = fc2b[2048 + tid], biasb = fc2b[2176 + tid];
#pragma unroll
  for (int r = 0; r < 32; r++) {
    float g = __fadd_rn(accg[r], biasg);
    float bb = __fadd_rn(accb[r], biasb);
    float t1 = __fadd_rn(1.0f, g);
    c_mod[(r0 + r) * H_ + tid] = __fadd_rn(__fmul_rn(t1, cj), bb);
  }
}

// bsum: one thread per row, exact sequential ascending order (certified)
__global__ __launch_bounds__(64) void k_bsum(const float* __restrict__ b_mod,
                                             float* __restrict__ bsum) {
  int row = blockIdx.x * 64 + threadIdx.x;
  const float4* bp = (const float4*)(b_mod + (size_t)row * V_);
  float acc = 0.0f;
  for (int c = 0; c < 32; c++) {
    float4 Bv[8];
#pragma unroll
    for (int q = 0; q < 8; q++) Bv[q] = bp[c * 8 + q];
#pragma unroll
    for (int q = 0; q < 8; q++) {
      acc = __fadd_rn(acc, Bv[q].x);
      acc = __fadd_rn(acc, Bv[q].y);
      acc = __fadd_rn(acc, Bv[q].z);
      acc = __fadd_rn(acc, Bv[q].w);
    }
  }
  bsum[row] = acc;
}

// v0: store samp bits only (flip(v0, s0=1) == v0); out materialized by k_fin.
__global__ void k_v0(uint32_t* __restrict__ v_bits, float* __restrict__ s0,
                     uint32_t kva, uint32_t kvb) {
  int idx = blockIdx.x * blockDim.x + threadIdx.x;
  int row = idx >> 10, col = idx & 1023;
  uint32_t bits = draw_bits(kva, kvb, (uint32_t)idx);
  float u = bits_to_u(bits);
  unsigned long long m = __ballot(u < 0.5f);
  if ((threadIdx.x & 63) == 0) {
    v_bits[row * 32 + (col >> 5)] = (uint32_t)m;
    v_bits[row * 32 + (col >> 5) + 1] = (uint32_t)(m >> 32);
  }
  if (col == 0) s0[row] = 1.0f;
}

// ---------------- per-step kernels ----------------
// K1: p_h = sigmoid((v_eff@W + c_mod)/T); h = bern(k1).
// v_eff == v_samp(prev) (double-flip identity) -> reads samp bits, no s0.
// 3-deep register pipeline: buffers B0/B1/B2 (8 float4 each), window w's loads
// issued 2 windows (~320 cyc DO8 compute) ahead of use. 512 blocks x 256 thr;
// 16 rows/block; ct=tid&31 (4 h-cols), rt=tid>>5 (2 rows). Certified math:
// brev-rotated mask -> sign-extend -> and -> v_pk_fma_f32, ascending k.
__global__ __launch_bounds__(256) void k_h(const float* __restrict__ W,
                   const float* __restrict__ c_mod, const uint32_t* __restrict__ v_bits,
                   uint32_t* __restrict__ h_bits, const float* __restrict__ temps,
                   int step, Keys kn) {
  __shared__ uint32_t nib[16][32];
  int tid = threadIdx.x;
  int ct = tid & 31;
  int rt = tid >> 5; // 0..7
  int h0 = ct << 2;
  int row0 = blockIdx.x * 16 + rt * 2;
  float T = temps[step];
  f32x2 a00 = {0.f, 0.f}, a01 = {0.f, 0.f};
  f32x2 a10 = {0.f, 0.f}, a11 = {0.f, 0.f};
  const float* wp = W + h0;
  const uint4* vb0q = (const uint4*)(v_bits + (size_t)row0 * 32);
  const uint4* vb1q = (const uint4*)(v_bits + (size_t)(row0 + 1) * 32);

  float4 B0[8], B1[8], B2[8];
  uint32_t m0, m1;
  auto LOADW = [&](float4* d, int kbase) {
#pragma unroll
    for (int i = 0; i < 8; i++)
      d[i] = *(const float4*)(wp + (size_t)(kbase + i) * H_);
  };
  auto DO8 = [&](const float4* wv) {
#pragma unroll
    for (int j = 0; j < 8; j++) {
      uint32_t s0m = (uint32_t)((int32_t)m0 >> 31); m0 <<= 1;
      uint32_t s1m = (uint32_t)((int32_t)m1 >> 31); m1 <<= 1;
      float bf0 = __uint_as_float(s0m & 0x3f800000u);
      float bf1 = __uint_as_float(s1m & 0x3f800000u);
      f32x2 wlo = {wv[j].x, wv[j].y};
      f32x2 whi = {wv[j].z, wv[j].w};
      f32x2 b0 = {bf0, bf0};
      f32x2 b1 = {bf1, bf1};
      pkfma(a00, wlo, b0); pkfma(a01, whi, b0);
      pkfma(a10, wlo, b1); pkfma(a11, whi, b1);
    }
  };
#define BUFSEL_(i) ((i) % 3 == 0 ? B0 : ((i) % 3 == 1 ? B1 : B2))

  uint4 q0 = vb0q[0], q1 = vb1q[0];
  uint4 q0n, q1n;
  LOADW(B0, 0);
  LOADW(B1, 8);
  // 128 windows of 8 k; mask word = w>>2 within uint4 (w>>4); 3-buffer rotation.
#pragma unroll
  for (int w = 0; w < 128; w++) {
    if ((w & 15) == 0) {
      const int kq = w >> 4;
      if (kq > 0) { q0 = q0n; q1 = q1n; }
      if (kq < 7) { q0n = vb0q[kq + 1]; q1n = vb1q[kq + 1]; }
    }
    if ((w & 3) == 0) {
      const int wi = (w >> 2) & 3;
      uint32_t t0 = wi == 0 ? q0.x : wi == 1 ? q0.y : wi == 2 ? q0.z : q0.w;
      uint32_t t1 = wi == 0 ? q1.x : wi == 1 ? q1.y : wi == 2 ? q1.z : q1.w;
      m0 = __brev(t0);
      m1 = __brev(t1);
    }
    if (w + 2 < 128) LOADW(BUFSEL_(w + 2), (w + 2) * 8);
    DO8(BUFSEL_(w));
  }
#undef BUFSEL_

  // epilogue: p, bern draw, nibble pack
  const f32x2* accs[2][2] = {{&a00, &a01}, {&a10, &a11}};
#pragma unroll
  for (int r = 0; r < 2; r++) {
    int row = row0 + r;
    float4 cm = *(const float4*)(c_mod + (size_t)row * H_ + h0);
    const float cma[4] = {cm.x, cm.y, cm.z, cm.w};
    const float ac[4] = {(*accs[r][0])[0], (*accs[r][0])[1],
                         (*accs[r][1])[0], (*accs[r][1])[1]};
    uint32_t nb = 0;
#pragma unroll
    for (int e = 0; e < 4; e++) {
      float z = __fadd_rn(ac[e], cma[e]) / T;
      float p = sigmoid_a(z);
      uint32_t b = draw_bits(kn.a[0], kn.a[1], (uint32_t)(row * H_ + h0 + e));
      if (bits_to_u(b) < p) nb |= 1u << e;
    }
    nib[rt * 2 + r][ct] = nb;
  }
  __syncthreads();
  if (tid < 64) {
    int rloc = tid >> 2, wq = tid & 3;
    uint32_t word = 0;
#pragma unroll
    for (int i = 0; i < 8; i++) word |= nib[rloc][wq * 8 + i] << (4 * i);
    h_bits[(size_t)(blockIdx.x * 16 + rloc) * 4 + wq] = word;
  }
}

// K2+K4 fused: a = h @ W.T (ascending-h adds, certified order), then the
// v-sampling epilogue directly from the in-register a values:
// z=(a+b_mod)/T -> sigmoid_a -> threefry draw -> nibble pack -> vb_new.
// Sampling is independent of s0n (double-flip identity; flip applied at k_fin).
// 256 threads: ct=tid&63 (4 v-cols), rt=tid>>6 (8 rows) -> 32 rows/block.
__global__ __launch_bounds__(256) void k_a(const float* __restrict__ WT,
                   const uint32_t* __restrict__ h_bits, const float* __restrict__ b_mod,
                   float* __restrict__ a, uint32_t* __restrict__ vb_new,
                   const float* __restrict__ temps, int step, Keys kn) {
  __shared__ uint32_t nib[32][65]; // padded: pack-read spreads banks
  int tid = threadIdx.x;
  int ct = tid & 63;
  int rt = tid >> 6;
  int v0 = blockIdx.x * 256 + (ct << 2);
  int r0 = blockIdx.y * 32 + rt * 8;
  f32x2 acc[8][2];
#pragma unroll
  for (int r = 0; r < 8; r++) { acc[r][0] = f32x2{0.f, 0.f}; acc[r][1] = f32x2{0.f, 0.f}; }
  uint4 hw[8];
#pragma unroll
  for (int r = 0; r < 8; r++) hw[r] = *(const uint4*)(h_bits + (size_t)(r0 + r) * 4);
  const float* wp0 = WT + v0;

  uint32_t m[8];
  float4 buf0[4], buf1[4];
  auto LOADG = [&](float4* d, int g) {
    const float* wp = wp0 + (size_t)(g * 4) * V_;
#pragma unroll
    for (int jj = 0; jj < 4; jj++) d[jj] = *(const float4*)(wp + (size_t)jj * V_);
  };
  auto COMP = [&](const float4* d) {
#pragma unroll
    for (int jj = 0; jj < 4; jj++) {
      f32x2 wlo = {d[jj].x, d[jj].y};
      f32x2 whi = {d[jj].z, d[jj].w};
#pragma unroll
      for (int r = 0; r < 8; r++) {
        uint32_t sm = (uint32_t)((int32_t)m[r] >> 31);
        m[r] <<= 1;
        float bf = __uint_as_float(sm & 0x3f800000u);
        f32x2 b2 = {bf, bf};
        pkfma(acc[r][0], wlo, b2);
        pkfma(acc[r][1], whi, b2);
      }
    }
  };

  LOADG(buf0, 0);
#pragma unroll
  for (int g = 0; g < 32; g++) {
    if ((g & 7) == 0) {
      const int s = g >> 3;
#pragma unroll
      for (int r = 0; r < 8; r++)
        m[r] = __brev(s == 0 ? hw[r].x : s == 1 ? hw[r].y : s == 2 ? hw[r].z : hw[r].w);
    }
    if (g & 1) { if (g < 31) LOADG(buf0, g + 1); COMP(buf1); }
    else       { if (g < 31) LOADG(buf1, g + 1); COMP(buf0); }
  }

  // epilogue: store a; sample v_samp bits (certified z/sigmoid/threefry chain)
  float T = temps[step];
#pragma unroll
  for (int r = 0; r < 8; r++) {
    int row = r0 + r;
    float4 av = make_float4(acc[r][0][0], acc[r][0][1], acc[r][1][0], acc[r][1][1]);
    *(float4*)(a + (size_t)row * V_ + v0) = av;
    float4 bv = *(const float4*)(b_mod + (size_t)row * V_ + v0);
    const float ax[4] = {av.x, av.y, av.z, av.w};
    const float bx[4] = {bv.x, bv.y, bv.z, bv.w};
    uint32_t nb = 0;
#pragma unroll
    for (int e = 0; e < 4; e++) {
      float z = __fadd_rn(ax[e], bx[e]) / T;
      float p = sigmoid_a(z);
      uint32_t bits = draw_bits(kn.a[4], kn.a[5], (uint32_t)(row * V_ + v0 + e));
      float u = bits_to_u(bits);
      if (u < p) nb |= 1u << e;
    }
    nib[rt * 8 + r][ct] = nb;
  }
  __syncthreads();
  {
    // 256 threads pack 32 rows x 8 words; word = cols bx*256+32*wq+[0,32)
    int rloc = tid >> 3, wq = tid & 7;
    uint32_t word = 0;
#pragma unroll
    for (int i = 0; i < 8; i++) word |= nib[rloc][wq * 8 + i] << (4 * i);
    vb_new[(size_t)(blockIdx.y * 32 + rloc) * 32 + blockIdx.x * 8 + wq] = word;
  }
}

// K3: chains-only (round-9 proven). LDS-staged a/b chunks; 16 chain threads
// run the certified sequential chains (ascending col, verbatim order);
// v = samp(prev) ^ flip(s0_old). Reads old s0, writes new s0.
__global__ __launch_bounds__(256) void k_s0(const float* __restrict__ a,
                     const float* __restrict__ b_mod, const float* __restrict__ bsum,
                     const uint32_t* __restrict__ vb_old, float* __restrict__ s0,
                     const float* __restrict__ temps, int step, Keys kn) {
  __shared__ float As[2][16][132];
  __shared__ float Bs[2][16][132];
  int tid = threadIdx.x;
  int r0 = blockIdx.x * 16;

  auto STAGE = [&](int buf, int c) {
#pragma unroll
    for (int i = 0; i < 2; i++) {
      int e = tid + i * 256;   // 0..511 float4 slots (16 rows x 32 float4)
      int r = e >> 5, c4 = e & 31;
      float4 av = *(const float4*)(a + (size_t)(r0 + r) * V_ + c * 128 + c4 * 4);
      float4 bv = *(const float4*)(b_mod + (size_t)(r0 + r) * V_ + c * 128 + c4 * 4);
      *(float4*)&As[buf][r][c4 * 4] = av;
      *(float4*)&Bs[buf][r][c4 * 4] = bv;
    }
  };

  float suma = 0.0f, vb = 0.0f, va = 0.0f;
  uint32_t flipm = 0;
  if (tid < 16) flipm = (s0[r0 + tid] == 0.0f) ? 0xFFFFFFFFu : 0u;
  STAGE(0, 0);
  __syncthreads();
  for (int c = 0; c < 8; c++) {
    if (c < 7) STAGE((c + 1) & 1, c + 1);
    if (tid < 16) {
      int row = r0 + tid;
      uint4 mw = *(const uint4*)(vb_old + (size_t)row * 32 + c * 4);
      const uint32_t mm[4] = {mw.x ^ flipm, mw.y ^ flipm, mw.z ^ flipm, mw.w ^ flipm};
#pragma unroll
      for (int w4 = 0; w4 < 4; w4++) {
        uint32_t m = mm[w4];
#pragma unroll
        for (int j4 = 0; j4 < 8; j4++) {
          float4 av4 = *(const float4*)&As[c & 1][tid][w4 * 32 + j4 * 4];
          float4 bv4 = *(const float4*)&Bs[c & 1][tid][w4 * 32 + j4 * 4];
          const float ax[4] = {av4.x, av4.y, av4.z, av4.w};
          const float bx[4] = {bv4.x, bv4.y, bv4.z, bv4.w};
#pragma unroll
          for (int e = 0; e < 4; e++) {
            float bit = (float)((m >> (j4 * 4 + e)) & 1u);
            suma = __fadd_rn(suma, ax[e]);
            vb = __fmaf_rn(bx[e], bit, vb);
            va = __fmaf_rn(ax[e], bit, va);
          }
        }
      }
    }
    __syncthreads();
  }
  if (tid < 16) {
    int row = r0 + tid;
    float dE = __fsub_rn(-bsum[row], suma);
    dE = __fadd_rn(dE, __fmul_rn(2.0f, vb));
    dE = __fadd_rn(dE, __fmul_rn(2.0f, va));
    float T = temps[step];
    float p = sigmoid_a(dE / T);
    uint32_t bits = draw_bits(kn.a[2], kn.a[3], (uint32_t)row);
    float u = bits_to_u(bits);
    s0[row] = (u < p) ? 1.0f : 0.0f;
  }
}

// Final: out = flip(v_samp(15), s0n(15)) — the only full vout write.
__global__ void k_fin(const uint32_t* __restrict__ v_bits, const float* __restrict__ s0,
                      float* __restrict__ vout) {
  int idx = blockIdx.x * blockDim.x + threadIdx.x;
  int row = idx >> 10, col = idx & 1023;
  uint32_t w = v_bits[row * 32 + (col >> 5)];
  uint32_t bit = (w >> (col & 31)) & 1u;
  uint32_t eff = (s0[row] != 0.0f) ? bit : (bit ^ 1u);
  vout[idx] = (float)eff;
}

extern "C" void kernel_launch(void* const* d_in, const int* in_sizes, int n_in,
                              void* d_out, int out_size, void* d_ws, size_t ws_size,
                              hipStream_t stream) {
  const float* cond = (const float*)d_in[0];
  const float* W = (const float*)d_in[1];
  const float* bvec = (const float*)d_in[2];
  const float* cvec = (const float*)d_in[3];
  const float* fc1w = (const float*)d_in[4];
  const float* fc1b = (const float*)d_in[5];
  const float* fc2w = (const float*)d_in[6];
  const float* fc2b = (const float*)d_in[7];
  const float* falloff = (const float*)d_in[8];
  float* out = (float*)d_out;

  char* ws = (char*)d_ws;
  size_t off = 0;
  auto alloc = [&](size_t bytes) { void* p = ws + off; off += (bytes + 255) & ~(size_t)255; return p; };
  float* b_mod = (float*)alloc((size_t)B_ * V_ * 4);
  float* c_mod = (float*)alloc((size_t)B_ * H_ * 4);
  float* abuf  = (float*)alloc((size_t)B_ * V_ * 4);
  float* xmlp  = (float*)alloc((size_t)B_ * WID_ * 4);
  float* bsum  = (float*)alloc((size_t)B_ * 4);
  float* s0    = (float*)alloc((size_t)B_ * 4);
  uint32_t* v_bits0 = (uint32_t*)alloc((size_t)B_ * 32 * 4);
  uint32_t* v_bits1 = (uint32_t*)alloc((size_t)B_ * 32 * 4);
  uint32_t* h_bits = (uint32_t*)alloc((size_t)B_ * 4 * 4);
  float* WT    = (float*)alloc((size_t)H_ * V_ * 4);
  float* fc2T  = (float*)alloc((size_t)WID_ * NOUT_ * 4);
  float* temps = (float*)alloc(16 * 4);
  uint32_t* vb[2] = {v_bits0, v_bits1};

  // host-side key derivation (threefry): base = key(42) = (0,42)
  uint32_t kva, kvb;
  tf2x32(0u, 42u, 0u, 1048576u, &kva, &kvb); // fold_in(base, 2**20) for v0
  Keys kn[16];
  for (int i = 0; i < 16; i++) {
    uint32_t f0, f1;
    tf2x32(0u, 42u, 0u, (uint32_t)i, &f0, &f1); // fold_in(base, i)
    uint32_t a0, a1;
    tf2x32(f0, f1, 0u, 0u, &a0, &a1); kn[i].a[0] = a0; kn[i].a[1] = a1;
    tf2x32(f0, f1, 0u, 1u, &a0, &a1); kn[i].a[2] = a0; kn[i].a[3] = a1;
    tf2x32(f0, f1, 0u, 2u, &a0, &a1); kn[i].a[4] = a0; kn[i].a[5] = a1;
  }

  // ---- setup ----
  k_transpose<<<(NOUT_ * WID_ + 255) / 256, 256, 0, stream>>>(W, WT, fc2w, fc2T);
  k_temps<<<1, 64, 0, stream>>>(falloff, temps);
  k_mlp1<<<(B_ * WID_) / 256, 256, 0, stream>>>(cond, fc1w, fc1b, xmlp);
  k_mlp2b<<<dim3(8, 256), 128, 0, stream>>>(xmlp, fc2T, fc2b, bvec, b_mod);
  k_mlp2c<<<dim3(1, 256), 128, 0, stream>>>(xmlp, fc2T, fc2b, cvec, c_mod);
  k_bsum<<<B_ / 64, 64, 0, stream>>>(b_mod, bsum);
  k_v0<<<(B_ * V_) / 256, 256, 0, stream>>>(vb[0], s0, kva, kvb);

  // ---- 16 Gibbs steps ----
  for (int i = 0; i < STEPS_; i++) {
    k_h<<<B_ / 16, 256, 0, stream>>>(W, c_mod, vb[i & 1], h_bits, temps, i, kn[i]);
    k_a<<<dim3(4, B_ / 32), 256, 0, stream>>>(WT, h_bits, b_mod, abuf,
                                              vb[(i + 1) & 1], temps, i, kn[i]);
    k_s0<<<B_ / 16, 256, 0, stream>>>(abuf, b_mod, bsum, vb[i & 1], s0, temps, i, kn[i]);
  }

  // ---- materialize output once ----
  k_fin<<<(B_ * V_) / 256, 256, 0, stream>>>(vb[0], s0, out);
}

// Round 15
// 2866.302 us; speedup vs baseline: 6.6560x; 6.6560x over previous
//
#include <hip/hip_runtime.h>
#include <stdint.h>

#pragma clang fp contract(off)

#define B_ 8192
#define V_ 1024
#define H_ 128
#define CD_ 16
#define WID_ 64
#define NOUT_ 2304
#define STEPS_ 16

typedef float f32x2 __attribute__((ext_vector_type(2)));

// packed f32 fma: per-half IEEE rn fma — bit-identical to the certified
// scalar __fmaf_rn(wv, bit, acc) applied to each half independently.
__device__ __forceinline__ void pkfma(f32x2& acc, f32x2 wv, f32x2 bf2) {
  asm("v_pk_fma_f32 %0, %1, %2, %0" : "+v"(acc) : "v"(wv), "v"(bf2));
}

// ---------------- threefry2x32 (JAX-compatible, 20 rounds) ----------------
__host__ __device__ __forceinline__ void tf2x32(uint32_t k0, uint32_t k1,
                                                uint32_t x0, uint32_t x1,
                                                uint32_t* o0, uint32_t* o1) {
  uint32_t ks2 = k0 ^ k1 ^ 0x1BD11BDAu;
#define RL_(v, d) (((v) << (d)) | ((v) >> (32 - (d))))
#define RND_(a) { x0 += x1; x1 = RL_(x1, a); x1 ^= x0; }
  x0 += k0; x1 += k1;
  RND_(13) RND_(15) RND_(26) RND_(6)
  x0 += k1; x1 += ks2 + 1u;
  RND_(17) RND_(29) RND_(16) RND_(24)
  x0 += ks2; x1 += k0 + 2u;
  RND_(13) RND_(15) RND_(26) RND_(6)
  x0 += k0; x1 += k1 + 3u;
  RND_(17) RND_(29) RND_(16) RND_(24)
  x0 += k1; x1 += ks2 + 4u;
  RND_(13) RND_(15) RND_(26) RND_(6)
  x0 += ks2; x1 += k0 + 5u;
#undef RND_
#undef RL_
  *o0 = x0; *o1 = x1;
}

struct Keys { uint32_t a[6]; }; // (k1a,k1b,k2a,k2b,k3a,k3b)

// certified: partitionable threefry, bits = x0 ^ x1
__device__ __forceinline__ uint32_t draw_bits(uint32_t ka, uint32_t kb, uint32_t j) {
  uint32_t x0, x1;
  tf2x32(ka, kb, 0u, j, &x0, &x1);
  return x0 ^ x1;
}

__device__ __forceinline__ float bits_to_u(uint32_t bits) {
  return __fsub_rn(__uint_as_float((bits >> 9) | 0x3f800000u), 1.0f); // exact
}

// certified config A: XLA Cephes exp, plain mul/add
__device__ __forceinline__ float exp_a(float x) {
  float xc = fminf(fmaxf(x, -88.3762626647949f), 88.3762626647950f);
  float fx = floorf(__fadd_rn(__fmul_rn(xc, 1.44269504088896341f), 0.5f));
  float xr = __fsub_rn(xc, __fmul_rn(0.693359375f, fx));
  xr = __fsub_rn(xr, __fmul_rn(-2.12194440e-4f, fx));
  float zz = __fmul_rn(xr, xr);
  float y = 1.9875691500E-4f;
  y = __fadd_rn(__fmul_rn(y, xr), 1.3981999507E-3f);
  y = __fadd_rn(__fmul_rn(y, xr), 8.3334519073E-3f);
  y = __fadd_rn(__fmul_rn(y, xr), 4.1665795894E-2f);
  y = __fadd_rn(__fmul_rn(y, xr), 1.6666665459E-1f);
  y = __fadd_rn(__fmul_rn(y, xr), 5.0000001201E-1f);
  y = __fadd_rn(__fmul_rn(y, zz), xr);
  y = __fadd_rn(y, 1.0f);
  int n = (int)fx;
  float sc = __int_as_float((n + 127) << 23);
  return __fmul_rn(y, sc);
}

// certified config A: XLA EmitFastTanh, plain path (for the MLP tanh)
__device__ __forceinline__ float tanh_a(float xin) {
  float x = fmaxf(fminf(xin, 7.90531110763549805f), -7.90531110763549805f);
  float x2 = __fmul_rn(x, x);
  float p = __fadd_rn(__fmul_rn(x2, -2.76076847742355e-16f), 2.00018790482477e-13f);
  p = __fadd_rn(__fmul_rn(x2, p), -8.60467152213735e-11f);
  p = __fadd_rn(__fmul_rn(x2, p), 5.12229709037114e-08f);
  p = __fadd_rn(__fmul_rn(x2, p), 1.48572235717979e-05f);
  p = __fadd_rn(__fmul_rn(x2, p), 6.37261928875436e-04f);
  p = __fadd_rn(__fmul_rn(x2, p), 4.89352455891786e-03f);
  p = __fmul_rn(x, p);
  float q = __fadd_rn(__fmul_rn(x2, 1.19825839466702e-06f), 1.18534705686654e-04f);
  q = __fadd_rn(__fmul_rn(x2, q), 2.26843463243900e-03f);
  q = __fadd_rn(__fmul_rn(x2, q), 4.89352518554385e-03f);
  float r = p / q;
  if (fabsf(xin) < 0.0004f) r = xin;
  return r;
}

// certified: exp-form logistic
__device__ __forceinline__ float sigmoid_a(float z) {
  float e = exp_a(-z);
  return 1.0f / __fadd_rn(1.0f, e);
}

// ---------------- setup kernels ----------------
__global__ void k_transpose(const float* __restrict__ W, float* __restrict__ WT,
                            const float* __restrict__ fc2w, float* __restrict__ fc2T) {
  int i = blockIdx.x * blockDim.x + threadIdx.x;
  if (i < V_ * H_) { int v = i / H_, h = i % H_; WT[h * V_ + v] = W[i]; }
  if (i < NOUT_ * WID_) { int j = i / WID_, w = i % WID_; fc2T[w * NOUT_ + j] = fc2w[i]; }
}

__global__ void k_temps(const float* __restrict__ falloff, float* __restrict__ temps) {
  int t = threadIdx.x;
  if (t < 16) {
    float arg = __fmul_rn(*falloff, __fsub_rn((float)t, 8.0f));
    float e = exp_a(arg);
    float s = 1.0f / __fadd_rn(1.0f, e);
    temps[t] = __fadd_rn(1.0f, __fmul_rn(4.0f, s));
  }
}

__global__ void k_mlp1(const float* __restrict__ cond, const float* __restrict__ fc1w,
                       const float* __restrict__ fc1b, float* __restrict__ xout) {
  int idx = blockIdx.x * blockDim.x + threadIdx.x;
  if (idx >= B_ * WID_) return;
  int row = idx >> 6, w = idx & 63;
  float acc = 0.0f;
  for (int k = 0; k < CD_; k++) acc = __fmaf_rn(cond[row * CD_ + k], fc1w[w * CD_ + k], acc);
  float z = __fadd_rn(acc, fc1b[w]);
  xout[idx] = tanh_a(z);
}

__global__ __launch_bounds__(128) void k_mlp2b(const float* __restrict__ xmlp,
                       const float* __restrict__ fc2T, const float* __restrict__ fc2b,
                       const float* __restrict__ bvec, float* __restrict__ b_mod) {
  __shared__ float xs[32][WID_];
  int jbase = blockIdx.x * 128;
  int r0 = blockIdx.y * 32;
  int tid = threadIdx.x;
  for (int t = tid; t < 32 * WID_; t += 128)
    xs[t >> 6][t & 63] = xmlp[(r0 + (t >> 6)) * WID_ + (t & 63)];
  __syncthreads();
  int j = jbase + tid;
  float accg[32], accb[32];
#pragma unroll
  for (int r = 0; r < 32; r++) { accg[r] = 0.0f; accb[r] = 0.0f; }
  for (int w = 0; w < WID_; w++) {
    float fg = fc2T[w * NOUT_ + j];
    float fb = fc2T[w * NOUT_ + 1024 + j];
#pragma unroll
    for (int r = 0; r < 32; r++) {
      float xv = xs[r][w];
      accg[r] = __fmaf_rn(xv, fg, accg[r]);
      accb[r] = __fmaf_rn(xv, fb, accb[r]);
    }
  }
  float bj = bvec[j];
  float biasg = fc2b[j], biasb = fc2b[1024 + j];
#pragma unroll
  for (int r = 0; r < 32; r++) {
    float g = __fadd_rn(accg[r], biasg);
    float bb = __fadd_rn(accb[r], biasb);
    float t1 = __fadd_rn(1.0f, g);
    b_mod[(r0 + r) * V_ + j] = __fadd_rn(__fmul_rn(t1, bj), bb);
  }
}

__global__ __launch_bounds__(128) void k_mlp2c(const float* __restrict__ xmlp,
                       const float* __restrict__ fc2T, const float* __restrict__ fc2b,
                       const float* __restrict__ cvec, float* __restrict__ c_mod) {
  __shared__ float xs[32][WID_];
  int r0 = blockIdx.y * 32;
  int tid = threadIdx.x; // 0..127
  for (int t = tid; t < 32 * WID_; t += 128)
    xs[t >> 6][t & 63] = xmlp[(r0 + (t >> 6)) * WID_ + (t & 63)];
  __syncthreads();
  float accg[32], accb[32];
#pragma unroll
  for (int r = 0; r < 32; r++) { accg[r] = 0.0f; accb[r] = 0.0f; }
  for (int w = 0; w < WID_; w++) {
    float fg = fc2T[w * NOUT_ + 2048 + tid];
    float fb = fc2T[w * NOUT_ + 2176 + tid];
#pragma unroll
    for (int r = 0; r < 32; r++) {
      float xv = xs[r][w];
      accg[r] = __fmaf_rn(xv, fg, accg[r]);
      accb[r] = __fmaf_rn(xv, fb, accb[r]);
    }
  }
  float cj = cvec[tid];
  float biasg = fc2b[2048 + tid], biasb = fc2b[2176 + tid];
#pragma unroll
  for (int r = 0; r < 32; r++) {
    float g = __fadd_rn(accg[r], biasg);
    float bb = __fadd_rn(accb[r], biasb);
    float t1 = __fadd_rn(1.0f, g);
    c_mod[(r0 + r) * H_ + tid] = __fadd_rn(__fmul_rn(t1, cj), bb);
  }
}

// bsum: one thread per row, exact sequential ascending order (certified)
__global__ __launch_bounds__(64) void k_bsum(const float* __restrict__ b_mod,
                                             float* __restrict__ bsum) {
  int row = blockIdx.x * 64 + threadIdx.x;
  const float4* bp = (const float4*)(b_mod + (size_t)row * V_);
  float acc = 0.0f;
  for (int c = 0; c < 32; c++) {
    float4 Bv[8];
#pragma unroll
    for (int q = 0; q < 8; q++) Bv[q] = bp[c * 8 + q];
#pragma unroll
    for (int q = 0; q < 8; q++) {
      acc = __fadd_rn(acc, Bv[q].x);
      acc = __fadd_rn(acc, Bv[q].y);
      acc = __fadd_rn(acc, Bv[q].z);
      acc = __fadd_rn(acc, Bv[q].w);
    }
  }
  bsum[row] = acc;
}

// v0: store samp bits only (flip(v0, s0=1) == v0); out materialized by k_fin.
__global__ void k_v0(uint32_t* __restrict__ v_bits, float* __restrict__ s0,
                     uint32_t kva, uint32_t kvb) {
  int idx = blockIdx.x * blockDim.x + threadIdx.x;
  int row = idx >> 10, col = idx & 1023;
  uint32_t bits = draw_bits(kva, kvb, (uint32_t)idx);
  float u = bits_to_u(bits);
  unsigned long long m = __ballot(u < 0.5f);
  if ((threadIdx.x & 63) == 0) {
    v_bits[row * 32 + (col >> 5)] = (uint32_t)m;
    v_bits[row * 32 + (col >> 5) + 1] = (uint32_t)(m >> 32);
  }
  if (col == 0) s0[row] = 1.0f;
}

// ---------------- per-step kernels ----------------
// K1: p_h = sigmoid((v_eff@W + c_mod)/T); h = bern(k1).
// v_eff == v_samp(prev) (double-flip identity) -> reads samp bits, no s0.
// Round-9 proven schedule: 2 NAMED register buffers (A/Bq ping-pong — no
// pointer selection, SROA-safe), 8-load windows, loads 1 window ahead.
// 512 blocks x 256 threads; 16 rows/block; ct=tid&31 (4 h-cols), rt=tid>>5
// (2 rows). Certified math: brev-rotated mask -> sign-extend -> and ->
// v_pk_fma_f32, strictly ascending k (bit-exact vs rounds 2-13).
__global__ __launch_bounds__(256) void k_h(const float* __restrict__ W,
                   const float* __restrict__ c_mod, const uint32_t* __restrict__ v_bits,
                   uint32_t* __restrict__ h_bits, const float* __restrict__ temps,
                   int step, Keys kn) {
  __shared__ uint32_t nib[16][32];
  int tid = threadIdx.x;
  int ct = tid & 31;
  int rt = tid >> 5; // 0..7
  int h0 = ct << 2;
  int row0 = blockIdx.x * 16 + rt * 2;
  float T = temps[step];
  f32x2 a00 = {0.f, 0.f}, a01 = {0.f, 0.f};
  f32x2 a10 = {0.f, 0.f}, a11 = {0.f, 0.f};
  const float* wp = W + h0;
  const uint4* vb0q = (const uint4*)(v_bits + (size_t)row0 * 32);
  const uint4* vb1q = (const uint4*)(v_bits + (size_t)(row0 + 1) * 32);

  float4 A[8], Bq[8];
  uint32_t m0, m1;
  auto LOADW = [&](float4* d, int kbase) {
#pragma unroll
    for (int i = 0; i < 8; i++)
      d[i] = *(const float4*)(wp + (size_t)(kbase + i) * H_);
  };
  auto DO8 = [&](const float4* wv) {
#pragma unroll
    for (int j = 0; j < 8; j++) {
      uint32_t s0m = (uint32_t)((int32_t)m0 >> 31); m0 <<= 1;
      uint32_t s1m = (uint32_t)((int32_t)m1 >> 31); m1 <<= 1;
      float bf0 = __uint_as_float(s0m & 0x3f800000u);
      float bf1 = __uint_as_float(s1m & 0x3f800000u);
      f32x2 wlo = {wv[j].x, wv[j].y};
      f32x2 whi = {wv[j].z, wv[j].w};
      f32x2 b0 = {bf0, bf0};
      f32x2 b1 = {bf1, bf1};
      pkfma(a00, wlo, b0); pkfma(a01, whi, b0);
      pkfma(a10, wlo, b1); pkfma(a11, whi, b1);
    }
  };

  uint4 q0 = vb0q[0], q1 = vb1q[0];
  uint4 q0n, q1n;
  LOADW(A, 0);
  for (int kq = 0; kq < 8; kq++) {
    if (kq < 7) { q0n = vb0q[kq + 1]; q1n = vb1q[kq + 1]; }
    const uint32_t w0s[4] = {q0.x, q0.y, q0.z, q0.w};
    const uint32_t w1s[4] = {q1.x, q1.y, q1.z, q1.w};
#pragma unroll
    for (int wq = 0; wq < 4; wq++) {
      int kb = kq * 128 + wq * 32;
      m0 = __brev(w0s[wq]);
      m1 = __brev(w1s[wq]);
      LOADW(Bq, kb + 8);  DO8(A);
      LOADW(A, kb + 16);  DO8(Bq);
      LOADW(Bq, kb + 24); DO8(A);
      if (kb + 32 < 1024) LOADW(A, kb + 32);
      DO8(Bq);
    }
    q0 = q0n; q1 = q1n;
  }

  // epilogue: p, bern draw, nibble pack
  const f32x2* accs[2][2] = {{&a00, &a01}, {&a10, &a11}};
#pragma unroll
  for (int r = 0; r < 2; r++) {
    int row = row0 + r;
    float4 cm = *(const float4*)(c_mod + (size_t)row * H_ + h0);
    const float cma[4] = {cm.x, cm.y, cm.z, cm.w};
    const float ac[4] = {(*accs[r][0])[0], (*accs[r][0])[1],
                         (*accs[r][1])[0], (*accs[r][1])[1]};
    uint32_t nb = 0;
#pragma unroll
    for (int e = 0; e < 4; e++) {
      float z = __fadd_rn(ac[e], cma[e]) / T;
      float p = sigmoid_a(z);
      uint32_t b = draw_bits(kn.a[0], kn.a[1], (uint32_t)(row * H_ + h0 + e));
      if (bits_to_u(b) < p) nb |= 1u << e;
    }
    nib[rt * 2 + r][ct] = nb;
  }
  __syncthreads();
  if (tid < 64) {
    int rloc = tid >> 2, wq = tid & 3;
    uint32_t word = 0;
#pragma unroll
    for (int i = 0; i < 8; i++) word |= nib[rloc][wq * 8 + i] << (4 * i);
    h_bits[(size_t)(blockIdx.x * 16 + rloc) * 4 + wq] = word;
  }
}

// K2+K4 fused: a = h @ W.T (ascending-h adds, certified order), then the
// v-sampling epilogue directly from the in-register a values:
// z=(a+b_mod)/T -> sigmoid_a -> threefry draw -> nibble pack -> vb_new.
// Sampling is independent of s0n (double-flip identity; flip applied at k_fin).
// 256 threads: ct=tid&63 (4 v-cols), rt=tid>>6 (8 rows) -> 32 rows/block.
__global__ __launch_bounds__(256) void k_a(const float* __restrict__ WT,
                   const uint32_t* __restrict__ h_bits, const float* __restrict__ b_mod,
                   float* __restrict__ a, uint32_t* __restrict__ vb_new,
                   const float* __restrict__ temps, int step, Keys kn) {
  __shared__ uint32_t nib[32][65]; // padded: pack-read spreads banks
  int tid = threadIdx.x;
  int ct = tid & 63;
  int rt = tid >> 6;
  int v0 = blockIdx.x * 256 + (ct << 2);
  int r0 = blockIdx.y * 32 + rt * 8;
  f32x2 acc[8][2];
#pragma unroll
  for (int r = 0; r < 8; r++) { acc[r][0] = f32x2{0.f, 0.f}; acc[r][1] = f32x2{0.f, 0.f}; }
  uint4 hw[8];
#pragma unroll
  for (int r = 0; r < 8; r++) hw[r] = *(const uint4*)(h_bits + (size_t)(r0 + r) * 4);
  const float* wp0 = WT + v0;

  uint32_t m[8];
  float4 buf0[4], buf1[4];
  auto LOADG = [&](float4* d, int g) {
    const float* wp = wp0 + (size_t)(g * 4) * V_;
#pragma unroll
    for (int jj = 0; jj < 4; jj++) d[jj] = *(const float4*)(wp + (size_t)jj * V_);
  };
  auto COMP = [&](const float4* d) {
#pragma unroll
    for (int jj = 0; jj < 4; jj++) {
      f32x2 wlo = {d[jj].x, d[jj].y};
      f32x2 whi = {d[jj].z, d[jj].w};
#pragma unroll
      for (int r = 0; r < 8; r++) {
        uint32_t sm = (uint32_t)((int32_t)m[r] >> 31);
        m[r] <<= 1;
        float bf = __uint_as_float(sm & 0x3f800000u);
        f32x2 b2 = {bf, bf};
        pkfma(acc[r][0], wlo, b2);
        pkfma(acc[r][1], whi, b2);
      }
    }
  };

  LOADG(buf0, 0);
#pragma unroll
  for (int g = 0; g < 32; g++) {
    if ((g & 7) == 0) {
      const int s = g >> 3;
#pragma unroll
      for (int r = 0; r < 8; r++)
        m[r] = __brev(s == 0 ? hw[r].x : s == 1 ? hw[r].y : s == 2 ? hw[r].z : hw[r].w);
    }
    if (g & 1) { if (g < 31) LOADG(buf0, g + 1); COMP(buf1); }
    else       { if (g < 31) LOADG(buf1, g + 1); COMP(buf0); }
  }

  // epilogue: store a; sample v_samp bits (certified z/sigmoid/threefry chain)
  float T = temps[step];
#pragma unroll
  for (int r = 0; r < 8; r++) {
    int row = r0 + r;
    float4 av = make_float4(acc[r][0][0], acc[r][0][1], acc[r][1][0], acc[r][1][1]);
    *(float4*)(a + (size_t)row * V_ + v0) = av;
    float4 bv = *(const float4*)(b_mod + (size_t)row * V_ + v0);
    const float ax[4] = {av.x, av.y, av.z, av.w};
    const float bx[4] = {bv.x, bv.y, bv.z, bv.w};
    uint32_t nb = 0;
#pragma unroll
    for (int e = 0; e < 4; e++) {
      float z = __fadd_rn(ax[e], bx[e]) / T;
      float p = sigmoid_a(z);
      uint32_t bits = draw_bits(kn.a[4], kn.a[5], (uint32_t)(row * V_ + v0 + e));
      float u = bits_to_u(bits);
      if (u < p) nb |= 1u << e;
    }
    nib[rt * 8 + r][ct] = nb;
  }
  __syncthreads();
  {
    // 256 threads pack 32 rows x 8 words; word = cols bx*256+32*wq+[0,32)
    int rloc = tid >> 3, wq = tid & 7;
    uint32_t word = 0;
#pragma unroll
    for (int i = 0; i < 8; i++) word |= nib[rloc][wq * 8 + i] << (4 * i);
    vb_new[(size_t)(blockIdx.y * 32 + rloc) * 32 + blockIdx.x * 8 + wq] = word;
  }
}

// K3: chains-only (round-9 proven). LDS-staged a/b chunks; 16 chain threads
// run the certified sequential chains (ascending col, verbatim order);
// v = samp(prev) ^ flip(s0_old). Reads old s0, writes new s0.
__global__ __launch_bounds__(256) void k_s0(const float* __restrict__ a,
                     const float* __restrict__ b_mod, const float* __restrict__ bsum,
                     const uint32_t* __restrict__ vb_old, float* __restrict__ s0,
                     const float* __restrict__ temps, int step, Keys kn) {
  __shared__ float As[2][16][132];
  __shared__ float Bs[2][16][132];
  int tid = threadIdx.x;
  int r0 = blockIdx.x * 16;

  auto STAGE = [&](int buf, int c) {
#pragma unroll
    for (int i = 0; i < 2; i++) {
      int e = tid + i * 256;   // 0..511 float4 slots (16 rows x 32 float4)
      int r = e >> 5, c4 = e & 31;
      float4 av = *(const float4*)(a + (size_t)(r0 + r) * V_ + c * 128 + c4 * 4);
      float4 bv = *(const float4*)(b_mod + (size_t)(r0 + r) * V_ + c * 128 + c4 * 4);
      *(float4*)&As[buf][r][c4 * 4] = av;
      *(float4*)&Bs[buf][r][c4 * 4] = bv;
    }
  };

  float suma = 0.0f, vb = 0.0f, va = 0.0f;
  uint32_t flipm = 0;
  if (tid < 16) flipm = (s0[r0 + tid] == 0.0f) ? 0xFFFFFFFFu : 0u;
  STAGE(0, 0);
  __syncthreads();
  for (int c = 0; c < 8; c++) {
    if (c < 7) STAGE((c + 1) & 1, c + 1);
    if (tid < 16) {
      int row = r0 + tid;
      uint4 mw = *(const uint4*)(vb_old + (size_t)row * 32 + c * 4);
      const uint32_t mm[4] = {mw.x ^ flipm, mw.y ^ flipm, mw.z ^ flipm, mw.w ^ flipm};
#pragma unroll
      for (int w4 = 0; w4 < 4; w4++) {
        uint32_t m = mm[w4];
#pragma unroll
        for (int j4 = 0; j4 < 8; j4++) {
          float4 av4 = *(const float4*)&As[c & 1][tid][w4 * 32 + j4 * 4];
          float4 bv4 = *(const float4*)&Bs[c & 1][tid][w4 * 32 + j4 * 4];
          const float ax[4] = {av4.x, av4.y, av4.z, av4.w};
          const float bx[4] = {bv4.x, bv4.y, bv4.z, bv4.w};
#pragma unroll
          for (int e = 0; e < 4; e++) {
            float bit = (float)((m >> (j4 * 4 + e)) & 1u);
            suma = __fadd_rn(suma, ax[e]);
            vb = __fmaf_rn(bx[e], bit, vb);
            va = __fmaf_rn(ax[e], bit, va);
          }
        }
      }
    }
    __syncthreads();
  }
  if (tid < 16) {
    int row = r0 + tid;
    float dE = __fsub_rn(-bsum[row], suma);
    dE = __fadd_rn(dE, __fmul_rn(2.0f, vb));
    dE = __fadd_rn(dE, __fmul_rn(2.0f, va));
    float T = temps[step];
    float p = sigmoid_a(dE / T);
    uint32_t bits = draw_bits(kn.a[2], kn.a[3], (uint32_t)row);
    float u = bits_to_u(bits);
    s0[row] = (u < p) ? 1.0f : 0.0f;
  }
}

// Final: out = flip(v_samp(15), s0n(15)) — the only full vout write.
__global__ void k_fin(const uint32_t* __restrict__ v_bits, const float* __restrict__ s0,
                      float* __restrict__ vout) {
  int idx = blockIdx.x * blockDim.x + threadIdx.x;
  int row = idx >> 10, col = idx & 1023;
  uint32_t w = v_bits[row * 32 + (col >> 5)];
  uint32_t bit = (w >> (col & 31)) & 1u;
  uint32_t eff = (s0[row] != 0.0f) ? bit : (bit ^ 1u);
  vout[idx] = (float)eff;
}

extern "C" void kernel_launch(void* const* d_in, const int* in_sizes, int n_in,
                              void* d_out, int out_size, void* d_ws, size_t ws_size,
                              hipStream_t stream) {
  const float* cond = (const float*)d_in[0];
  const float* W = (const float*)d_in[1];
  const float* bvec = (const float*)d_in[2];
  const float* cvec = (const float*)d_in[3];
  const float* fc1w = (const float*)d_in[4];
  const float* fc1b = (const float*)d_in[5];
  const float* fc2w = (const float*)d_in[6];
  const float* fc2b = (const float*)d_in[7];
  const float* falloff = (const float*)d_in[8];
  float* out = (float*)d_out;

  char* ws = (char*)d_ws;
  size_t off = 0;
  auto alloc = [&](size_t bytes) { void* p = ws + off; off += (bytes + 255) & ~(size_t)255; return p; };
  float* b_mod = (float*)alloc((size_t)B_ * V_ * 4);
  float* c_mod = (float*)alloc((size_t)B_ * H_ * 4);
  float* abuf  = (float*)alloc((size_t)B_ * V_ * 4);
  float* xmlp  = (float*)alloc((size_t)B_ * WID_ * 4);
  float* bsum  = (float*)alloc((size_t)B_ * 4);
  float* s0    = (float*)alloc((size_t)B_ * 4);
  uint32_t* v_bits0 = (uint32_t*)alloc((size_t)B_ * 32 * 4);
  uint32_t* v_bits1 = (uint32_t*)alloc((size_t)B_ * 32 * 4);
  uint32_t* h_bits = (uint32_t*)alloc((size_t)B_ * 4 * 4);
  float* WT    = (float*)alloc((size_t)H_ * V_ * 4);
  float* fc2T  = (float*)alloc((size_t)WID_ * NOUT_ * 4);
  float* temps = (float*)alloc(16 * 4);
  uint32_t* vb[2] = {v_bits0, v_bits1};

  // host-side key derivation (threefry): base = key(42) = (0,42)
  uint32_t kva, kvb;
  tf2x32(0u, 42u, 0u, 1048576u, &kva, &kvb); // fold_in(base, 2**20) for v0
  Keys kn[16];
  for (int i = 0; i < 16; i++) {
    uint32_t f0, f1;
    tf2x32(0u, 42u, 0u, (uint32_t)i, &f0, &f1); // fold_in(base, i)
    uint32_t a0, a1;
    tf2x32(f0, f1, 0u, 0u, &a0, &a1); kn[i].a[0] = a0; kn[i].a[1] = a1;
    tf2x32(f0, f1, 0u, 1u, &a0, &a1); kn[i].a[2] = a0; kn[i].a[3] = a1;
    tf2x32(f0, f1, 0u, 2u, &a0, &a1); kn[i].a[4] = a0; kn[i].a[5] = a1;
  }

  // ---- setup ----
  k_transpose<<<(NOUT_ * WID_ + 255) / 256, 256, 0, stream>>>(W, WT, fc2w, fc2T);
  k_temps<<<1, 64, 0, stream>>>(falloff, temps);
  k_mlp1<<<(B_ * WID_) / 256, 256, 0, stream>>>(cond, fc1w, fc1b, xmlp);
  k_mlp2b<<<dim3(8, 256), 128, 0, stream>>>(xmlp, fc2T, fc2b, bvec, b_mod);
  k_mlp2c<<<dim3(1, 256), 128, 0, stream>>>(xmlp, fc2T, fc2b, cvec, c_mod);
  k_bsum<<<B_ / 64, 64, 0, stream>>>(b_mod, bsum);
  k_v0<<<(B_ * V_) / 256, 256, 0, stream>>>(vb[0], s0, kva, kvb);

  // ---- 16 Gibbs steps ----
  for (int i = 0; i < STEPS_; i++) {
    k_h<<<B_ / 16, 256, 0, stream>>>(W, c_mod, vb[i & 1], h_bits, temps, i, kn[i]);
    k_a<<<dim3(4, B_ / 32), 256, 0, stream>>>(WT, h_bits, b_mod, abuf,
                                              vb[(i + 1) & 1], temps, i, kn[i]);
    k_s0<<<B_ / 16, 256, 0, stream>>>(abuf, b_mod, bsum, vb[i & 1], s0, temps, i, kn[i]);
  }

  // ---- materialize output once ----
  k_fin<<<(B_ * V_) / 256, 256, 0, stream>>>(vb[0], s0, out);
}